// Round 26
// baseline (50.077 us; speedup 1.0000x reference)
//
#include <hip/hip_runtime.h>

#define NB 4
#define NCI 64
#define NCO 64
#define PLANE 65536

// workspace offsets (in floats)
#define OF_XS_RE 0
#define OF_XS_IM (OF_XS_RE + PLANE)

// stage1 LDS plane layout (per buffer)
#define XEOFF(w) ((w)*260)
#define XOOFF(w) (16*260 + 8 + (w)*260)

#define TPF 6.2831853071795864769f

// Fused stage 1+2 (R25 structure) + phase-B RADIX-4 h-fold:
// (h, h+64, h+128, h+192) combine via (-i)^(kx*m) factors -> 16 folded quads
// per thread (was 32 folded pairs), rotation/FMA work drops ~25%.
__global__ __launch_bounds__(1024, 4) void k12_dft(const float* __restrict__ x,
                                                   float* __restrict__ ws) {
  __shared__ float bufA[8336], bufB[8336];
  __shared__ float cst[256], snt[256];
  __shared__ float2 s2[1024];
  const int t = threadIdx.x;
  const int img = blockIdx.x;

  if (t < 256) {
    float sv_, cv_;
    sincosf(TPF * (float)t * (1.0f/256.0f), &sv_, &cv_);
    cst[t] = cv_;  snt[t] = sv_;
  }

  const int sl = t & 3, row = t >> 2;
  const int wq = t & 3, p = (t >> 2) & 1;
  const int kg = (t >> 3) & 1, tr = t >> 4;
  int kyv[4];
#pragma unroll
  for (int j = 0; j < 4; ++j) kyv[j] = p + 8*kg + 2*j;

  const float* xb = x + (size_t)img * 65536;

  float4 lo0 = *(const float4*)(xb + row*256 + sl*4);
  float4 hi0 = *(const float4*)(xb + row*256 + 128 + sl*4);
  float4 lo1 = *(const float4*)(xb + row*256 + 16 + sl*4);
  float4 hi1 = *(const float4*)(xb + row*256 + 144 + sl*4);

  __syncthreads();                     // cst/snt ready

  float cd[4], sd[4];
#pragma unroll
  for (int j = 0; j < 4; ++j) { cd[j] = cst[kyv[j]]; sd[j] = snt[kyv[j]]; }

  float ar[4][4], ai[4][4];
#pragma unroll
  for (int j = 0; j < 4; ++j)
#pragma unroll
    for (int r = 0; r < 4; ++r) { ar[j][r] = 0.f; ai[j][r] = 0.f; }

  bufA[XEOFF(sl*4+0) + row] = lo0.x + hi0.x;
  bufA[XEOFF(sl*4+1) + row] = lo0.y + hi0.y;
  bufA[XEOFF(sl*4+2) + row] = lo0.z + hi0.z;
  bufA[XEOFF(sl*4+3) + row] = lo0.w + hi0.w;
  bufA[XOOFF(sl*4+0) + row] = lo0.x - hi0.x;
  bufA[XOOFF(sl*4+1) + row] = lo0.y - hi0.y;
  bufA[XOOFF(sl*4+2) + row] = lo0.z - hi0.z;
  bufA[XOOFF(sl*4+3) + row] = lo0.w - hi0.w;
  __syncthreads();                     // chunk 0 staged

  const int pofs = p ? (16*260 + 8) : 0;

  for (int c = 0; c < 8; ++c) {        // ROLLED — do not unroll (spill)
    float* cur = (c & 1) ? bufB : bufA;
    float* nxt = (c & 1) ? bufA : bufB;
    if (c < 6) {                       // issue chunk c+2 into slot (c&1)
      const int w0n = (c+2) * 16;
      if (c & 1) {
        lo1 = *(const float4*)(xb + row*256 + w0n + sl*4);
        hi1 = *(const float4*)(xb + row*256 + w0n + 128 + sl*4);
      } else {
        lo0 = *(const float4*)(xb + row*256 + w0n + sl*4);
        hi0 = *(const float4*)(xb + row*256 + w0n + 128 + sl*4);
      }
    }
    float cc[4], sv[4];
#pragma unroll
    for (int j = 0; j < 4; ++j) {
      const int m = (kyv[j] * (c*16 + wq*4)) & 255;
      cc[j] = cst[m];
      sv[j] = snt[m];
    }
    const float* rp = cur + pofs;
#pragma unroll
    for (int i = 0; i < 4; ++i) {
      const int wl = wq*4 + i;
      const float4 xs4 = *(const float4*)&rp[wl*260 + tr*4];
#pragma unroll
      for (int j = 0; j < 4; ++j) {
        ar[j][0] += xs4.x * cc[j];  ai[j][0] -= xs4.x * sv[j];
        ar[j][1] += xs4.y * cc[j];  ai[j][1] -= xs4.y * sv[j];
        ar[j][2] += xs4.z * cc[j];  ai[j][2] -= xs4.z * sv[j];
        ar[j][3] += xs4.w * cc[j];  ai[j][3] -= xs4.w * sv[j];
        const float nc = cc[j]*cd[j] - sv[j]*sd[j];
        const float ns = sv[j]*cd[j] + cc[j]*sd[j];
        cc[j] = nc; sv[j] = ns;
      }
    }
    if (c < 7) {
      if (c & 1) {
        nxt[XEOFF(sl*4+0) + row] = lo0.x + hi0.x;
        nxt[XEOFF(sl*4+1) + row] = lo0.y + hi0.y;
        nxt[XEOFF(sl*4+2) + row] = lo0.z + hi0.z;
        nxt[XEOFF(sl*4+3) + row] = lo0.w + hi0.w;
        nxt[XOOFF(sl*4+0) + row] = lo0.x - hi0.x;
        nxt[XOOFF(sl*4+1) + row] = lo0.y - hi0.y;
        nxt[XOOFF(sl*4+2) + row] = lo0.z - hi0.z;
        nxt[XOOFF(sl*4+3) + row] = lo0.w - hi0.w;
      } else {
        nxt[XEOFF(sl*4+0) + row] = lo1.x + hi1.x;
        nxt[XEOFF(sl*4+1) + row] = lo1.y + hi1.y;
        nxt[XEOFF(sl*4+2) + row] = lo1.z + hi1.z;
        nxt[XEOFF(sl*4+3) + row] = lo1.w + hi1.w;
        nxt[XOOFF(sl*4+0) + row] = lo1.x - hi1.x;
        nxt[XOOFF(sl*4+1) + row] = lo1.y - hi1.y;
        nxt[XOOFF(sl*4+2) + row] = lo1.z - hi1.z;
        nxt[XOOFF(sl*4+3) + row] = lo1.w - hi1.w;
      }
    }
    __syncthreads();                   // ONE barrier per chunk
  }

#pragma unroll
  for (int j = 0; j < 4; ++j)
#pragma unroll
    for (int r = 0; r < 4; ++r) {
      ar[j][r] += __shfl_xor(ar[j][r], 1);
      ar[j][r] += __shfl_xor(ar[j][r], 2);
      ai[j][r] += __shfl_xor(ai[j][r], 1);
      ai[j][r] += __shfl_xor(ai[j][r], 2);
    }
  if (wq == 0) {
#pragma unroll
    for (int j = 0; j < 4; ++j) {
      const int ky = kyv[j];
      float4 sr; sr.x = ar[j][0]; sr.y = ar[j][1]; sr.z = ar[j][2]; sr.w = ar[j][3];
      float4 si; si.x = ai[j][0]; si.y = ai[j][1]; si.z = ai[j][2]; si.w = ai[j][3];
      *(float4*)&bufA[XEOFF(ky) + tr*4] = sr;
      *(float4*)&bufA[XOOFF(ky) + tr*4] = si;
    }
  }
  __syncthreads();

  // phase B: h-DFT with RADIX-4 h-fold. c4 = kx&3:
  //   u = t0 + A*t1 + B*(i-swap t1), t0 = x_h + g*x_{h+128}, t1 = x_{h+64} + g*x_{h+192}
  //   g = (-1)^c4 parity; A = +-1 even c4; B = +-1 odd c4 (branchless consts).
  const int ky2 = t & 15, kx = (t >> 4) & 15, hh = t >> 8;
  const int c4 = kx & 3;
  const float g  = (c4 & 1) ? -1.f : 1.f;
  const float A  = (c4 == 0) ? 1.f : ((c4 == 2) ? -1.f : 0.f);
  const float B  = (c4 == 1) ? 1.f : ((c4 == 3) ? -1.f : 0.f);
  const float cdk = cst[kx], sdk = snt[kx];
  const int m0 = (kx * hh * 16) & 255;
  float cR = cst[m0], sR = snt[m0];
  float arr = 0.f, aii = 0.f;
  const int be = XEOFF(ky2) + hh*16;
  const int bo = XOOFF(ky2) + hh*16;
#pragma unroll
  for (int hq = 0; hq < 4; ++hq) {
    const float4 r0 = *(const float4*)&bufA[be + hq*4];
    const float4 r1 = *(const float4*)&bufA[be + 64 + hq*4];
    const float4 r2 = *(const float4*)&bufA[be + 128 + hq*4];
    const float4 r3 = *(const float4*)&bufA[be + 192 + hq*4];
    const float4 i0 = *(const float4*)&bufA[bo + hq*4];
    const float4 i1 = *(const float4*)&bufA[bo + 64 + hq*4];
    const float4 i2 = *(const float4*)&bufA[bo + 128 + hq*4];
    const float4 i3 = *(const float4*)&bufA[bo + 192 + hq*4];
    {
      const float t0r = r0.x + g*r2.x, t1r = r1.x + g*r3.x;
      const float t0i = i0.x + g*i2.x, t1i = i1.x + g*i3.x;
      const float ur = t0r + A*t1r + B*t1i;
      const float ui = t0i + A*t1i - B*t1r;
      arr += ur*cR + ui*sR;  aii += ui*cR - ur*sR;
      const float nc = cR*cdk - sR*sdk, ns = sR*cdk + cR*sdk; cR = nc; sR = ns;
    }
    {
      const float t0r = r0.y + g*r2.y, t1r = r1.y + g*r3.y;
      const float t0i = i0.y + g*i2.y, t1i = i1.y + g*i3.y;
      const float ur = t0r + A*t1r + B*t1i;
      const float ui = t0i + A*t1i - B*t1r;
      arr += ur*cR + ui*sR;  aii += ui*cR - ur*sR;
      const float nc = cR*cdk - sR*sdk, ns = sR*cdk + cR*sdk; cR = nc; sR = ns;
    }
    {
      const float t0r = r0.z + g*r2.z, t1r = r1.z + g*r3.z;
      const float t0i = i0.z + g*i2.z, t1i = i1.z + g*i3.z;
      const float ur = t0r + A*t1r + B*t1i;
      const float ui = t0i + A*t1i - B*t1r;
      arr += ur*cR + ui*sR;  aii += ui*cR - ur*sR;
      const float nc = cR*cdk - sR*sdk, ns = sR*cdk + cR*sdk; cR = nc; sR = ns;
    }
    {
      const float t0r = r0.w + g*r2.w, t1r = r1.w + g*r3.w;
      const float t0i = i0.w + g*i2.w, t1i = i1.w + g*i3.w;
      const float ur = t0r + A*t1r + B*t1i;
      const float ui = t0i + A*t1i - B*t1r;
      arr += ur*cR + ui*sR;  aii += ui*cR - ur*sR;
      const float nc = cR*cdk - sR*sdk, ns = sR*cdk + cR*sdk; cR = nc; sR = ns;
    }
  }
  s2[t].x = arr; s2[t].y = aii;
  __syncthreads();
  if (t < 256) {
    float xre = s2[t].x + s2[t+256].x + s2[t+512].x + s2[t+768].x;
    float xim = s2[t].y + s2[t+256].y + s2[t+512].y + s2[t+768].y;
    ws[OF_XS_RE + img*256 + t] = xre;
    ws[OF_XS_IM + img*256 + t] = xim;
  }
}

// Fused stage 3+4+5 (R25-verbatim).
__global__ __launch_bounds__(512, 2) void k345_idft(const float* __restrict__ w1r,
    const float* __restrict__ w1i, const float* __restrict__ w2r,
    const float* __restrict__ w2i, const float* __restrict__ ws,
    float* __restrict__ out) {
  __shared__ __align__(16) float o1r[256], o1i[256], o2r[256], o2i[256];
  __shared__ float cst[256], snt[256];
  __shared__ __align__(16) float Sr[256][20], Si[256][20];
  const int t  = threadIdx.x;
  const int bo = blockIdx.x;

  if (t < 256) {
    float sv_, cv_;
    sincosf(TPF * (float)t * (1.0f/256.0f), &sv_, &cv_);
    cst[t] = cv_;  snt[t] = sv_;
  }

  // ---- phase 0: mix, i-range split across thread halves ----
  {
    const int m = t & 255, ih = t >> 8;
    const int b = bo >> 6, o = bo & 63;
    const float* xsr = ws + OF_XS_RE;
    const float* xsi = ws + OF_XS_IM;
    float a1r=0.f, a1i=0.f, a2r=0.f, a2i=0.f;
#pragma unroll 4
    for (int ii = 0; ii < 32; ++ii) {
      const int i = ih*32 + ii;
      const int xi_ = ((b*NCI + i) << 8) + m;
      const float xr = xsr[xi_];
      const float xi = xsi[xi_];
      const int wi = ((i*NCO + o) << 8) + m;
      const float pw = w1r[wi], q = w1i[wi], u = w2r[wi], v = w2i[wi];
      a1r += xr*pw - xi*q;
      a1i += xr*q + xi*pw;
      a2r += xr*u - xi*v;
      a2i += xr*v + xi*u;
    }
    float4* pm1 = (float4*)&Sr[0][0];
    float4* pm2 = (float4*)&Si[0][0];
    float4 v1; v1.x = a1r; v1.y = a1i; v1.z = 0.f; v1.w = 0.f;
    float4 v2; v2.x = a2r; v2.y = a2i; v2.z = 0.f; v2.w = 0.f;
    pm1[t] = v1;
    pm2[t] = v2;
  }
  __syncthreads();
  if (t < 256) {
    const float4* pm1 = (const float4*)&Sr[0][0];
    const float4* pm2 = (const float4*)&Si[0][0];
    const float4 a = pm1[t], b4 = pm1[t + 256];
    const float4 c4 = pm2[t], d4 = pm2[t + 256];
    o1r[t] = a.x + b4.x;
    o1i[t] = a.y + b4.y;
    o2r[t] = c4.x + d4.x;
    o2i[t] = c4.y + d4.y;
  }
  __syncthreads();

  // ---- phase A (folded, h = 0..127) ----
  {
    const int h = t >> 2, kq = t & 3;
    const float chh = cst[h], shh = snt[h];
    float c1 = 1.f, s1 = 0.f;
    const int m2i = (240 * h) & 255;
    float cB = cst[m2i], sB = snt[m2i];
    float4 srE = {0,0,0,0}, siE = {0,0,0,0};
    float4 srO = {0,0,0,0}, siO = {0,0,0,0};
#pragma unroll
    for (int j = 0; j < 16; ++j) {
      const float4 r1 = *(const float4*)&o1r[j*16 + kq*4];
      const float4 i1 = *(const float4*)&o1i[j*16 + kq*4];
      const float4 r2 = *(const float4*)&o2r[j*16 + kq*4];
      const float4 i2 = *(const float4*)&o2i[j*16 + kq*4];
      float4& sr = (j & 1) ? srO : srE;
      float4& si = (j & 1) ? siO : siE;
      sr.x += r1.x*c1 - i1.x*s1 + r2.x*cB - i2.x*sB;
      si.x += r1.x*s1 + i1.x*c1 + r2.x*sB + i2.x*cB;
      sr.y += r1.y*c1 - i1.y*s1 + r2.y*cB - i2.y*sB;
      si.y += r1.y*s1 + i1.y*c1 + r2.y*sB + i2.y*cB;
      sr.z += r1.z*c1 - i1.z*s1 + r2.z*cB - i2.z*sB;
      si.z += r1.z*s1 + i1.z*c1 + r2.z*sB + i2.z*cB;
      sr.w += r1.w*c1 - i1.w*s1 + r2.w*cB - i2.w*sB;
      si.w += r1.w*s1 + i1.w*c1 + r2.w*sB + i2.w*cB;
      const float n1c = c1*chh - s1*shh, n1s = s1*chh + c1*shh;
      const float n2c = cB*chh - sB*shh, n2s = sB*chh + cB*shh;
      c1 = n1c; s1 = n1s; cB = n2c; sB = n2s;
    }
    float4 sp, sm;
    sp.x = srE.x + srO.x; sp.y = srE.y + srO.y; sp.z = srE.z + srO.z; sp.w = srE.w + srO.w;
    sm.x = srE.x - srO.x; sm.y = srE.y - srO.y; sm.z = srE.z - srO.z; sm.w = srE.w - srO.w;
    *(float4*)&Sr[h][kq*4]       = sp;
    *(float4*)&Sr[h+128][kq*4]   = sm;
    sp.x = siE.x + siO.x; sp.y = siE.y + siO.y; sp.z = siE.z + siO.z; sp.w = siE.w + siO.w;
    sm.x = siE.x - siO.x; sm.y = siE.y - siO.y; sm.z = siE.z - siO.z; sm.w = siE.w - siO.w;
    *(float4*)&Si[h][kq*4]       = sp;
    *(float4*)&Si[h+128][kq*4]   = sm;
  }
  __syncthreads();

  // ---- phase B trig ----
  const int wl = t & 31;
  float c[15], s[15], c2[15], s2[15];
#pragma unroll
  for (int k = 0; k < 15; ++k) {
    const int mi = ((k+1) * wl) & 255;
    c[k] = cst[mi];
    s[k] = snt[mi];
  }
  {
    const float R = 0.70710678118654752f;
#pragma unroll
    for (int k = 0; k < 15; ++k) {
      const int r8 = (k + 1) & 7;
      switch (r8) {
        case 0: c2[k] =  c[k];            s2[k] =  s[k];            break;
        case 1: c2[k] = (c[k]-s[k])*R;    s2[k] = (s[k]+c[k])*R;    break;
        case 2: c2[k] = -s[k];            s2[k] =  c[k];            break;
        case 3: c2[k] = -(c[k]+s[k])*R;   s2[k] = (c[k]-s[k])*R;    break;
        case 4: c2[k] = -c[k];            s2[k] = -s[k];            break;
        case 5: c2[k] = (s[k]-c[k])*R;    s2[k] = -(c[k]+s[k])*R;   break;
        case 6: c2[k] =  s[k];            s2[k] = -c[k];            break;
        default:c2[k] = (c[k]+s[k])*R;    s2[k] = (s[k]-c[k])*R;    break;
      }
    }
  }

  // ---- phase B: 256 rows, 8 waves x 32 rows, row-paired radix-4 ----
  const int half = (t >> 5) & 1;
  const int wv = t >> 6;
  const float scale = 2.0f / 65536.0f;
  const size_t base256 = (size_t)bo * 256;
#pragma unroll 2
  for (int pr = 0; pr < 16; ++pr) {
    const int lr = wv*32 + pr*2 + half;
    const float4 a0 = *(const float4*)&Sr[lr][0];
    const float4 a1 = *(const float4*)&Sr[lr][4];
    const float4 a2 = *(const float4*)&Sr[lr][8];
    const float4 a3 = *(const float4*)&Sr[lr][12];
    const float4 b0 = *(const float4*)&Si[lr][0];
    const float4 b1 = *(const float4*)&Si[lr][4];
    const float4 b2 = *(const float4*)&Si[lr][8];
    const float4 b3 = *(const float4*)&Si[lr][12];
    const float re[16] = {a0.x,a0.y,a0.z,a0.w, a1.x,a1.y,a1.z,a1.w,
                          a2.x,a2.y,a2.z,a2.w, a3.x,a3.y,a3.z,a3.w};
    const float im[16] = {b0.x,b0.y,b0.z,b0.w, b1.x,b1.y,b1.z,b1.w,
                          b2.x,b2.y,b2.z,b2.w, b3.x,b3.y,b3.z,b3.w};
    const size_t ob = (base256 + lr) * 256;

#pragma unroll
    for (int gg = 0; gg < 2; ++gg) {
      const float* cc = gg ? c2 : c;
      const float* ss = gg ? s2 : s;
      float PA = 0.5f * re[0];
      float PB = 0.f, PC = 0.f, PD = 0.f, QB = 0.f, QD = 0.f;
#pragma unroll
      for (int k = 0; k < 15; ++k) {
        const int ky = k + 1;
        const float R = re[ky], I = im[ky];
        const int cls = ky & 3;
        if (cls == 0)      PA += R*cc[k] - I*ss[k];
        else if (cls == 1) { PB += R*cc[k] - I*ss[k];  QB += R*ss[k] + I*cc[k]; }
        else if (cls == 2) PC += R*cc[k] - I*ss[k];
        else               { PD += R*cc[k] - I*ss[k];  QD += R*ss[k] + I*cc[k]; }
      }
      const float T1 = PA + PC, T2 = PB + PD;
      const float T3 = PA - PC, T4 = QB - QD;
      const int cb = wl + gg*32;
      out[ob + cb]       = (T1 + T2) * scale;
      out[ob + cb + 64]  = (T3 - T4) * scale;
      out[ob + cb + 128] = (T1 - T2) * scale;
      out[ob + cb + 192] = (T3 + T4) * scale;
    }
  }
}

extern "C" void kernel_launch(void* const* d_in, const int* in_sizes, int n_in,
                              void* d_out, int out_size, void* d_ws, size_t ws_size,
                              hipStream_t stream) {
  const float* x   = (const float*)d_in[0];
  const float* w1r = (const float*)d_in[1];
  const float* w1i = (const float*)d_in[2];
  const float* w2r = (const float*)d_in[3];
  const float* w2i = (const float*)d_in[4];
  float* out = (float*)d_out;
  float* ws  = (float*)d_ws;

  hipLaunchKernelGGL(k12_dft,   dim3(256), dim3(1024), 0, stream, x, ws);
  hipLaunchKernelGGL(k345_idft, dim3(256), dim3(512),  0, stream,
                     w1r, w1i, w2r, w2i, ws, out);
}